// Round 1
// baseline (347.871 us; speedup 1.0000x reference)
//
#include <hip/hip_runtime.h>
#include <hip/hip_bf16.h>

typedef unsigned short u16;
typedef __attribute__((ext_vector_type(8))) short short8;
typedef __attribute__((ext_vector_type(4))) float floatx4;

// ---- problem constants ----
#define BB 64
#define SS 192
#define DD 768
#define HH 3072
#define EE 6
#define PP 256
#define SHARED_N 512
#define M_TOT (BB * SS)          // 12288

#define GLD16(gp, lp) __builtin_amdgcn_global_load_lds(                         \
    (const __attribute__((address_space(1))) unsigned int*)(gp),                \
    (__attribute__((address_space(3))) unsigned int*)(lp), 16, 0, 0)

__device__ __forceinline__ u16 f2b(float x) {
  union { float f; unsigned u; } c; c.f = x;
  return (u16)((c.u + 0x7fffu + ((c.u >> 16) & 1u)) >> 16);  // RTNE
}

// ---------------- fp32 -> bf16 conversion, 8 elems/thread ----------------
__global__ __launch_bounds__(256) void cvt_kernel(const float* __restrict__ in,
                                                  u16* __restrict__ out, long n) {
  long i = ((long)blockIdx.x * blockDim.x + threadIdx.x) * 8;
  if (i >= n) return;
  float4 a = *(const float4*)(in + i);
  float4 b = *(const float4*)(in + i + 4);
  union { u16 us[8]; uint4 v; } r;
  r.us[0] = f2b(a.x); r.us[1] = f2b(a.y); r.us[2] = f2b(a.z); r.us[3] = f2b(a.w);
  r.us[4] = f2b(b.x); r.us[5] = f2b(b.y); r.us[6] = f2b(b.z); r.us[7] = f2b(b.w);
  *(uint4*)(out + i) = r.v;
}

// ---------------- GEMM1: h = gelu(X @ W1^T + b1), bf16 out ----------------
// X [12288,768] bf16, W1 [3072,768] bf16; tile 128x128, BK=32, m97 structure.
__global__ __launch_bounds__(256) void gemm1_kernel(const u16* __restrict__ X,
                                                    const u16* __restrict__ W,
                                                    const float* __restrict__ bias,
                                                    u16* __restrict__ H) {
  constexpr int K = DD;      // 768
  constexpr int N = HH;      // 3072
  __shared__ u16 As[128 * 32];
  __shared__ u16 Bs[128 * 32];
  const int tid = threadIdx.x;
  const int lane = tid & 63;
  const int wave = tid >> 6;
  const int m0 = blockIdx.x * 128;
  const int n0 = blockIdx.y * 128;
  const int wm = (wave >> 1) * 64;
  const int wn = (wave & 1) * 64;
  const int q = lane >> 4;
  const int r = lane & 15;

  floatx4 acc[4][4] = {};

  const int srow = tid >> 2;        // 0..63
  const int scol = (tid & 3) * 8;   // 0,8,16,24
  const u16* Ag = X + (long)(m0 + srow) * K + scol;
  const u16* Bg = W + (long)(n0 + srow) * K + scol;
  u16* Al = &As[srow * 32 + scol];
  u16* Bl = &Bs[srow * 32 + scol];

  for (int kt = 0; kt < K / 32; ++kt) {
    const int k0 = kt * 32;
    GLD16(Ag + k0, Al);
    GLD16(Ag + (long)64 * K + k0, Al + 64 * 32);
    GLD16(Bg + k0, Bl);
    GLD16(Bg + (long)64 * K + k0, Bl + 64 * 32);
    __syncthreads();
    short8 a[4], b[4];
#pragma unroll
    for (int i = 0; i < 4; ++i) a[i] = *(const short8*)&As[(wm + i * 16 + r) * 32 + q * 8];
#pragma unroll
    for (int j = 0; j < 4; ++j) b[j] = *(const short8*)&Bs[(wn + j * 16 + r) * 32 + q * 8];
#pragma unroll
    for (int i = 0; i < 4; ++i)
#pragma unroll
      for (int j = 0; j < 4; ++j)
        acc[i][j] = __builtin_amdgcn_mfma_f32_16x16x32_bf16(a[i], b[j], acc[i][j], 0, 0, 0);
    __syncthreads();
  }

#pragma unroll
  for (int j = 0; j < 4; ++j) {
    const int col = n0 + wn + j * 16 + r;
    const float bn = bias[col];
#pragma unroll
    for (int i = 0; i < 4; ++i) {
#pragma unroll
      for (int e = 0; e < 4; ++e) {
        const int row = m0 + wm + i * 16 + q * 4 + e;
        float v = acc[i][j][e] + bn;
        v = 0.5f * v * (1.0f + erff(v * 0.70710678118654752f));  // exact GELU
        H[(long)row * N + col] = f2b(v);
      }
    }
  }
}

// ---------------- GEMM2: out = h @ Wrow^T + bias, fp32 out ----------------
// BM=64 (divides 192 -> one batch per block), BN=128, BK=32.
// col tiles 0..3: fc2_w/fc2_b; col tiles 4..5: expert_w[idx]/expert_b[idx].
__global__ __launch_bounds__(256) void gemm2_kernel(const u16* __restrict__ Hb,
                                                    const u16* __restrict__ W2,
                                                    const u16* __restrict__ WE,
                                                    const float* __restrict__ b2,
                                                    const float* __restrict__ be,
                                                    const int* __restrict__ idx,
                                                    float* __restrict__ Out) {
  constexpr int K = HH;       // 3072
  constexpr int NOUT = DD;    // 768
  __shared__ u16 As[64 * 32];
  __shared__ u16 Bs[128 * 32];
  const int tid = threadIdx.x;
  const int lane = tid & 63;
  const int wave = tid >> 6;
  const int m0 = blockIdx.x * 64;
  const int n0 = blockIdx.y * 128;
  const int wn = wave * 32;   // 4 waves across N
  const int q = lane >> 4;
  const int r = lane & 15;

  const u16* Bbase;
  const float* biasp;
  if (n0 < SHARED_N) {
    Bbase = W2 + (long)n0 * K;
    biasp = b2 + n0;
  } else {
    const int e = idx[m0 / SS];
    Bbase = WE + ((long)e * PP + (n0 - SHARED_N)) * K;
    biasp = be + e * PP + (n0 - SHARED_N);
  }

  floatx4 acc[4][2] = {};

  const int srow = tid >> 2;
  const int scol = (tid & 3) * 8;
  const u16* Ag = Hb + (long)(m0 + srow) * K + scol;
  const u16* Bg = Bbase + (long)srow * K + scol;
  u16* Al = &As[srow * 32 + scol];
  u16* Bl = &Bs[srow * 32 + scol];

  for (int kt = 0; kt < K / 32; ++kt) {
    const int k0 = kt * 32;
    GLD16(Ag + k0, Al);
    GLD16(Bg + k0, Bl);
    GLD16(Bg + (long)64 * K + k0, Bl + 64 * 32);
    __syncthreads();
    short8 a[4], b[2];
#pragma unroll
    for (int i = 0; i < 4; ++i) a[i] = *(const short8*)&As[(i * 16 + r) * 32 + q * 8];
#pragma unroll
    for (int j = 0; j < 2; ++j) b[j] = *(const short8*)&Bs[(wn + j * 16 + r) * 32 + q * 8];
#pragma unroll
    for (int i = 0; i < 4; ++i)
#pragma unroll
      for (int j = 0; j < 2; ++j)
        acc[i][j] = __builtin_amdgcn_mfma_f32_16x16x32_bf16(a[i], b[j], acc[i][j], 0, 0, 0);
    __syncthreads();
  }

#pragma unroll
  for (int j = 0; j < 2; ++j) {
    const int cl = wn + j * 16 + r;      // 0..127 within tile
    const int col = n0 + cl;
    const float bn = biasp[cl];
#pragma unroll
    for (int i = 0; i < 4; ++i) {
#pragma unroll
      for (int e = 0; e < 4; ++e) {
        const int row = m0 + i * 16 + q * 4 + e;
        Out[(long)row * NOUT + col] = acc[i][j][e] + bn;
      }
    }
  }
}

extern "C" void kernel_launch(void* const* d_in, const int* in_sizes, int n_in,
                              void* d_out, int out_size, void* d_ws, size_t ws_size,
                              hipStream_t stream) {
  const float* x  = (const float*)d_in[0];   // [B,S,D]
  const int*  idx = (const int*)d_in[1];     // [B]
  const float* w1 = (const float*)d_in[2];   // [H,D]
  const float* b1 = (const float*)d_in[3];   // [H]
  const float* w2 = (const float*)d_in[4];   // [SHARED,H]
  const float* b2 = (const float*)d_in[5];   // [SHARED]
  const float* we = (const float*)d_in[6];   // [E,P,H]
  const float* be = (const float*)d_in[7];   // [E,P]
  float* out = (float*)d_out;

  // workspace layout (bf16 buffers), all 16B-aligned
  u16* Xb  = (u16*)d_ws;                              // 12288*768
  u16* W1b = Xb  + (long)M_TOT * DD;                  // 3072*768
  u16* W2b = W1b + (long)HH * DD;                     // 512*3072
  u16* WEb = W2b + (long)SHARED_N * HH;               // 6*256*3072
  u16* Hb  = WEb + (long)EE * PP * HH;                // 12288*3072

  const long nX  = (long)M_TOT * DD;      // 9,437,184
  const long nW1 = (long)HH * DD;         // 2,359,296
  const long nW2 = (long)SHARED_N * HH;   // 1,572,864
  const long nWE = (long)EE * PP * HH;    // 4,718,592

  cvt_kernel<<<(int)(nX  / 2048), 256, 0, stream>>>(x,  Xb,  nX);
  cvt_kernel<<<(int)(nW1 / 2048), 256, 0, stream>>>(w1, W1b, nW1);
  cvt_kernel<<<(int)(nW2 / 2048), 256, 0, stream>>>(w2, W2b, nW2);
  cvt_kernel<<<(int)(nWE / 2048), 256, 0, stream>>>(we, WEb, nWE);

  gemm1_kernel<<<dim3(M_TOT / 128, HH / 128), 256, 0, stream>>>(Xb, W1b, b1, Hb);
  gemm2_kernel<<<dim3(M_TOT / 64, DD / 128), 256, 0, stream>>>(Hb, W2b, WEb, b2, be, idx, out);
}

// Round 2
// 288.902 us; speedup vs baseline: 1.2041x; 1.2041x over previous
//
#include <hip/hip_runtime.h>
#include <hip/hip_bf16.h>

typedef unsigned short u16;
typedef __attribute__((ext_vector_type(8))) short short8;
typedef __attribute__((ext_vector_type(4))) float floatx4;

// ---- problem constants ----
#define BB 64
#define SS 192
#define DD 768
#define HH 3072
#define EE 6
#define PP 256
#define SHARED_N 512
#define M_TOT (BB * SS)          // 12288

#define GLD16(gp, lp) __builtin_amdgcn_global_load_lds(                         \
    (const __attribute__((address_space(1))) unsigned int*)(gp),                \
    (__attribute__((address_space(3))) unsigned int*)(lp), 16, 0, 0)

__device__ __forceinline__ u16 f2b(float x) {
  union { float f; unsigned u; } c; c.f = x;
  return (u16)((c.u + 0x7fffu + ((c.u >> 16) & 1u)) >> 16);  // RTNE
}

// -------- fp32 -> bf16 conversion, all 4 operands in ONE launch --------
// segment boundaries (elems) are multiples of 2048 -> block-uniform branch
#define N_X  9437184L   // 12288*768
#define N_W1 2359296L   // 3072*768
#define N_W2 1572864L   // 512*3072
#define N_WE 4718592L   // 6*256*3072
#define N_ALL (N_X + N_W1 + N_W2 + N_WE)  // 18087936

__global__ __launch_bounds__(256) void cvt_all_kernel(const float* __restrict__ x,
                                                      const float* __restrict__ w1,
                                                      const float* __restrict__ w2,
                                                      const float* __restrict__ we,
                                                      u16* __restrict__ dst) {
  long i = ((long)blockIdx.x * blockDim.x + threadIdx.x) * 8;
  const float* src;
  if (i < N_X)                  src = x  + i;
  else if (i < N_X + N_W1)      src = w1 + (i - N_X);
  else if (i < N_X + N_W1 + N_W2) src = w2 + (i - N_X - N_W1);
  else                          src = we + (i - N_X - N_W1 - N_W2);
  float4 a = *(const float4*)(src);
  float4 b = *(const float4*)(src + 4);
  union { u16 us[8]; uint4 v; } r;
  r.us[0] = f2b(a.x); r.us[1] = f2b(a.y); r.us[2] = f2b(a.z); r.us[3] = f2b(a.w);
  r.us[4] = f2b(b.x); r.us[5] = f2b(b.y); r.us[6] = f2b(b.z); r.us[7] = f2b(b.w);
  *(uint4*)(dst + i) = r.v;
}

// ---------------- GEMM1: h = gelu(X @ W1^T + b1), bf16 out ----------------
// X [12288,768] bf16, W1 [3072,768] bf16; tile 128x128, BK=32, m97 structure.
// (unchanged from R1 — verified correct, leave until counters say otherwise)
__global__ __launch_bounds__(256) void gemm1_kernel(const u16* __restrict__ X,
                                                    const u16* __restrict__ W,
                                                    const float* __restrict__ bias,
                                                    u16* __restrict__ H) {
  constexpr int K = DD;      // 768
  constexpr int N = HH;      // 3072
  __shared__ u16 As[128 * 32];
  __shared__ u16 Bs[128 * 32];
  const int tid = threadIdx.x;
  const int lane = tid & 63;
  const int wave = tid >> 6;
  const int m0 = blockIdx.x * 128;
  const int n0 = blockIdx.y * 128;
  const int wm = (wave >> 1) * 64;
  const int wn = (wave & 1) * 64;
  const int q = lane >> 4;
  const int r = lane & 15;

  floatx4 acc[4][4] = {};

  const int srow = tid >> 2;        // 0..63
  const int scol = (tid & 3) * 8;   // 0,8,16,24
  const u16* Ag = X + (long)(m0 + srow) * K + scol;
  const u16* Bg = W + (long)(n0 + srow) * K + scol;
  u16* Al = &As[srow * 32 + scol];
  u16* Bl = &Bs[srow * 32 + scol];

  for (int kt = 0; kt < K / 32; ++kt) {
    const int k0 = kt * 32;
    GLD16(Ag + k0, Al);
    GLD16(Ag + (long)64 * K + k0, Al + 64 * 32);
    GLD16(Bg + k0, Bl);
    GLD16(Bg + (long)64 * K + k0, Bl + 64 * 32);
    __syncthreads();
    short8 a[4], b[4];
#pragma unroll
    for (int i = 0; i < 4; ++i) a[i] = *(const short8*)&As[(wm + i * 16 + r) * 32 + q * 8];
#pragma unroll
    for (int j = 0; j < 4; ++j) b[j] = *(const short8*)&Bs[(wn + j * 16 + r) * 32 + q * 8];
#pragma unroll
    for (int i = 0; i < 4; ++i)
#pragma unroll
      for (int j = 0; j < 4; ++j)
        acc[i][j] = __builtin_amdgcn_mfma_f32_16x16x32_bf16(a[i], b[j], acc[i][j], 0, 0, 0);
    __syncthreads();
  }

#pragma unroll
  for (int j = 0; j < 4; ++j) {
    const int col = n0 + wn + j * 16 + r;
    const float bn = bias[col];
#pragma unroll
    for (int i = 0; i < 4; ++i) {
#pragma unroll
      for (int e = 0; e < 4; ++e) {
        const int row = m0 + wm + i * 16 + q * 4 + e;
        float v = acc[i][j][e] + bn;
        v = 0.5f * v * (1.0f + erff(v * 0.70710678118654752f));  // exact GELU
        H[(long)row * N + col] = f2b(v);
      }
    }
  }
}

// ---------------- GEMM2: out = h @ Wrow^T + bias, fp32 out ----------------
// BM=96 (divides 192 -> one batch per row-tile), BN=128, BK=64.
// Grid = 128 x 6 = 768 blocks = exactly 3/CU. 24 MFMA/wave per K-iter,
// 48 K-iters (half the barriers of BK=32).
// LDS: XOR-swizzled chunks. Chunk (row, kc) [16B each, 8 chunks/row] lives at
// LDS chunk row*8 + (kc ^ (row&7)). global_load_lds dest stays lane-contiguous
// (LDS chunk id = i*256+tid); the swizzle is applied on the GLOBAL source
// address, which is per-lane free. Fragment ds_read_b128 then touches all 32
// banks (2 lanes/bank-group = free), vs 16-way aliasing unswizzled at 128B row
// stride.
__global__ __launch_bounds__(256, 3) void gemm2_kernel(const u16* __restrict__ Hb,
                                                       const u16* __restrict__ W2,
                                                       const u16* __restrict__ WE,
                                                       const float* __restrict__ b2,
                                                       const float* __restrict__ be,
                                                       const int* __restrict__ idx,
                                                       float* __restrict__ Out) {
  constexpr int K = HH;       // 3072
  constexpr int NOUT = DD;    // 768
  __shared__ u16 As[96 * 64];    // 12 KB
  __shared__ u16 Bs[128 * 64];   // 16 KB
  const int tid = threadIdx.x;
  const int lane = tid & 63;
  const int wave = tid >> 6;
  const int m0 = blockIdx.x * 96;          // row tile, inside batch blockIdx.x>>1
  const int n0 = blockIdx.y * 128;         // col tile
  const int wm = (wave >> 1) * 48;         // wave tile 48x64 in 2x2 grid
  const int wn = (wave & 1) * 64;
  const int q = lane >> 4;
  const int r = lane & 15;
  const int xr = r & 7;                    // swizzle term for fragment reads

  const u16* Bbase;
  const float* biasp;
  if (n0 < SHARED_N) {
    Bbase = W2 + (long)n0 * K;
    biasp = b2 + n0;
  } else {
    const int e = idx[blockIdx.x >> 1];
    Bbase = WE + ((long)e * PP + (n0 - SHARED_N)) * K;
    biasp = be + e * PP + (n0 - SHARED_N);
  }
  const u16* Abase = Hb + (long)m0 * K;

  floatx4 acc[3][4] = {};

  // staging chunk assignments (K-invariant parts)
  int a_row[3], a_kcg[3], b_row[4], b_kcg[4];
#pragma unroll
  for (int i = 0; i < 3; ++i) {
    int c = i * 256 + tid;                 // A chunks: 96*8 = 768
    a_row[i] = c >> 3;
    a_kcg[i] = (c & 7) ^ (a_row[i] & 7);
  }
#pragma unroll
  for (int i = 0; i < 4; ++i) {
    int c = i * 256 + tid;                 // B chunks: 128*8 = 1024
    b_row[i] = c >> 3;
    b_kcg[i] = (c & 7) ^ (b_row[i] & 7);
  }

  for (int kt = 0; kt < K / 64; ++kt) {
    const int k0 = kt * 64;
#pragma unroll
    for (int i = 0; i < 3; ++i)
      GLD16(Abase + (long)a_row[i] * K + k0 + a_kcg[i] * 8, &As[(i * 256 + tid) * 8]);
#pragma unroll
    for (int i = 0; i < 4; ++i)
      GLD16(Bbase + (long)b_row[i] * K + k0 + b_kcg[i] * 8, &Bs[(i * 256 + tid) * 8]);
    __syncthreads();

    short8 a[2][3], b[2][4];
#pragma unroll
    for (int ks = 0; ks < 2; ++ks) {
      const int kc = ks * 4 + q;
#pragma unroll
      for (int i = 0; i < 3; ++i)
        a[ks][i] = *(const short8*)&As[(((wm + i * 16 + r) << 3) + (kc ^ xr)) << 3];
#pragma unroll
      for (int j = 0; j < 4; ++j)
        b[ks][j] = *(const short8*)&Bs[(((wn + j * 16 + r) << 3) + (kc ^ xr)) << 3];
    }
#pragma unroll
    for (int ks = 0; ks < 2; ++ks)
#pragma unroll
      for (int i = 0; i < 3; ++i)
#pragma unroll
        for (int j = 0; j < 4; ++j)
          acc[i][j] = __builtin_amdgcn_mfma_f32_16x16x32_bf16(a[ks][i], b[ks][j], acc[i][j], 0, 0, 0);
    __syncthreads();
  }

#pragma unroll
  for (int j = 0; j < 4; ++j) {
    const int cl = wn + j * 16 + r;        // 0..127 within tile
    const int col = n0 + cl;
    const float bn = biasp[cl];
#pragma unroll
    for (int i = 0; i < 3; ++i) {
#pragma unroll
      for (int e = 0; e < 4; ++e) {
        const int row = m0 + wm + i * 16 + q * 4 + e;
        Out[(long)row * NOUT + col] = acc[i][j][e] + bn;
      }
    }
  }
}

extern "C" void kernel_launch(void* const* d_in, const int* in_sizes, int n_in,
                              void* d_out, int out_size, void* d_ws, size_t ws_size,
                              hipStream_t stream) {
  const float* x  = (const float*)d_in[0];   // [B,S,D]
  const int*  idx = (const int*)d_in[1];     // [B]
  const float* w1 = (const float*)d_in[2];   // [H,D]
  const float* b1 = (const float*)d_in[3];   // [H]
  const float* w2 = (const float*)d_in[4];   // [SHARED,H]
  const float* b2 = (const float*)d_in[5];   // [SHARED]
  const float* we = (const float*)d_in[6];   // [E,P,H]
  const float* be = (const float*)d_in[7];   // [E,P]
  float* out = (float*)d_out;

  // workspace layout (bf16 buffers), contiguous so cvt_all writes one dst
  u16* Xb  = (u16*)d_ws;                              // 12288*768
  u16* W1b = Xb  + N_X;                               // 3072*768
  u16* W2b = W1b + N_W1;                              // 512*3072
  u16* WEb = W2b + N_W2;                              // 6*256*3072
  u16* Hb  = WEb + N_WE;                              // 12288*3072

  cvt_all_kernel<<<(int)(N_ALL / 2048), 256, 0, stream>>>(x, w1, w2, we, Xb);
  gemm1_kernel<<<dim3(M_TOT / 128, HH / 128), 256, 0, stream>>>(Xb, W1b, b1, Hb);
  gemm2_kernel<<<dim3(M_TOT / 96, DD / 128), 256, 0, stream>>>(Hb, W2b, WEb, b2, be, idx, out);
}

// Round 3
// 255.110 us; speedup vs baseline: 1.3636x; 1.1325x over previous
//
#include <hip/hip_runtime.h>
#include <hip/hip_bf16.h>

typedef unsigned short u16;
typedef __attribute__((ext_vector_type(8))) short short8;
typedef __attribute__((ext_vector_type(4))) float floatx4;

// ---- problem constants ----
#define BB 64
#define SS 192
#define DD 768
#define HH 3072
#define EE 6
#define PP 256
#define SHARED_N 512
#define M_TOT (BB * SS)          // 12288

#define GLD16(gp, lp) __builtin_amdgcn_global_load_lds(                         \
    (const __attribute__((address_space(1))) unsigned int*)(gp),                \
    (__attribute__((address_space(3))) unsigned int*)(lp), 16, 0, 0)

__device__ __forceinline__ u16 f2b(float x) {
  union { float f; unsigned u; } c; c.f = x;
  return (u16)((c.u + 0x7fffu + ((c.u >> 16) & 1u)) >> 16);  // RTNE
}

// tanh-form GELU via sigmoid identity: 0.5x(1+tanh(z)) == x*sigmoid(2z).
// exp2/rcp are single-inst HW approx. Max abs error vs exact-erf GELU ~3e-4,
// far below bf16 rounding of h (~2e-3) and the 3.9e-2 output threshold.
__device__ __forceinline__ float fast_gelu(float x) {
  const float c = 2.0f * 0.7978845608028654f * 1.4426950408889634f; // 2*sqrt(2/pi)*log2(e)
  float xp = __builtin_fmaf(0.044715f * x * x, x, x);
  float e = __builtin_amdgcn_exp2f(-c * xp);
  return x * __builtin_amdgcn_rcpf(1.0f + e);
}

// -------- fp32 -> bf16 conversion, all 4 operands in ONE launch --------
#define N_X  9437184L   // 12288*768
#define N_W1 2359296L   // 3072*768
#define N_W2 1572864L   // 512*3072
#define N_WE 4718592L   // 6*256*3072
#define N_ALL (N_X + N_W1 + N_W2 + N_WE)  // 18087936

__global__ __launch_bounds__(256) void cvt_all_kernel(const float* __restrict__ x,
                                                      const float* __restrict__ w1,
                                                      const float* __restrict__ w2,
                                                      const float* __restrict__ we,
                                                      u16* __restrict__ dst) {
  long i = ((long)blockIdx.x * blockDim.x + threadIdx.x) * 8;
  const float* src;
  if (i < N_X)                  src = x  + i;
  else if (i < N_X + N_W1)      src = w1 + (i - N_X);
  else if (i < N_X + N_W1 + N_W2) src = w2 + (i - N_X - N_W1);
  else                          src = we + (i - N_X - N_W1 - N_W2);
  float4 a = *(const float4*)(src);
  float4 b = *(const float4*)(src + 4);
  union { u16 us[8]; uint4 v; } r;
  r.us[0] = f2b(a.x); r.us[1] = f2b(a.y); r.us[2] = f2b(a.z); r.us[3] = f2b(a.w);
  r.us[4] = f2b(b.x); r.us[5] = f2b(b.y); r.us[6] = f2b(b.z); r.us[7] = f2b(b.w);
  *(uint4*)(dst + i) = r.v;
}

// ---------------- GEMM1: h = gelu(X @ W1^T + b1), bf16 out ----------------
// 128x128 tile, BK=64, XOR-swizzled LDS (gemm2-proven pattern). 12 K-iters,
// 32 MFMA/wave/iter. Epilogue: fast_gelu + LDS-staged coalesced dwordx4
// stores (fixes 2x write amplification seen in R2: WRITE_SIZE 152MB vs 75MB).
#define EPI_STRIDE 132   // 128+4: 264B row stride spreads q-groups across banks
__global__ __launch_bounds__(256, 3) void gemm1_kernel(const u16* __restrict__ X,
                                                       const u16* __restrict__ W,
                                                       const float* __restrict__ bias,
                                                       u16* __restrict__ H) {
  constexpr int K = DD;      // 768
  constexpr int N = HH;      // 3072
  __shared__ u16 smem[128 * EPI_STRIDE];   // 33792 B; K-loop uses first 32 KB
  u16* As = smem;            // 128*64
  u16* Bs = smem + 8192;     // 128*64
  const int tid = threadIdx.x;
  const int lane = tid & 63;
  const int wave = tid >> 6;
  const int m0 = blockIdx.x * 128;
  const int n0 = blockIdx.y * 128;
  const int wm = (wave >> 1) * 64;
  const int wn = (wave & 1) * 64;
  const int q = lane >> 4;
  const int r = lane & 15;
  const int xr = r & 7;

  floatx4 acc[4][4] = {};

  // staging chunk assignments: 128 rows x 8 chunks(16B) = 1024 chunks, 4/thread
  int rowc[4], kcg[4];
#pragma unroll
  for (int i = 0; i < 4; ++i) {
    int c = i * 256 + tid;
    rowc[i] = c >> 3;
    kcg[i] = (c & 7) ^ (rowc[i] & 7);
  }

  for (int kt = 0; kt < K / 64; ++kt) {
    const int k0 = kt * 64;
#pragma unroll
    for (int i = 0; i < 4; ++i)
      GLD16(X + (long)(m0 + rowc[i]) * K + k0 + kcg[i] * 8, &As[(i * 256 + tid) * 8]);
#pragma unroll
    for (int i = 0; i < 4; ++i)
      GLD16(W + (long)(n0 + rowc[i]) * K + k0 + kcg[i] * 8, &Bs[(i * 256 + tid) * 8]);
    __syncthreads();

#pragma unroll
    for (int ks = 0; ks < 2; ++ks) {
      const int kc = ks * 4 + q;
      short8 a[4], b[4];
#pragma unroll
      for (int i = 0; i < 4; ++i)
        a[i] = *(const short8*)&As[(((wm + i * 16 + r) << 3) + (kc ^ xr)) << 3];
#pragma unroll
      for (int j = 0; j < 4; ++j)
        b[j] = *(const short8*)&Bs[(((wn + j * 16 + r) << 3) + (kc ^ xr)) << 3];
#pragma unroll
      for (int i = 0; i < 4; ++i)
#pragma unroll
        for (int j = 0; j < 4; ++j)
          acc[i][j] = __builtin_amdgcn_mfma_f32_16x16x32_bf16(a[i], b[j], acc[i][j], 0, 0, 0);
    }
    __syncthreads();
  }
  // last loop barrier guarantees all frag reads done -> smem reusable

#pragma unroll
  for (int j = 0; j < 4; ++j) {
    const int cl = wn + j * 16 + r;
    const float bn = bias[n0 + cl];
#pragma unroll
    for (int i = 0; i < 4; ++i) {
#pragma unroll
      for (int e = 0; e < 4; ++e) {
        const int rl = wm + i * 16 + q * 4 + e;
        smem[rl * EPI_STRIDE + cl] = f2b(fast_gelu(acc[i][j][e] + bn));
      }
    }
  }
  __syncthreads();

  const int er = tid >> 4;            // 0..15
  const int ec = (tid & 15) * 8;      // 0..120
#pragma unroll
  for (int it = 0; it < 8; ++it) {
    const int rl = er + it * 16;
    uint4 v = *(const uint4*)&smem[rl * EPI_STRIDE + ec];
    *(uint4*)&H[(long)(m0 + rl) * N + n0 + ec] = v;
  }
}

// ---------------- GEMM2: out = h @ Wrow^T + bias, fp32 out ----------------
// BM=96 (one batch per row-tile), BN=128, BK=64, XOR-swizzled LDS.
// Grid = 128 x 6 = 768 blocks = exactly 3/CU. (unchanged from R2 — validated)
__global__ __launch_bounds__(256, 3) void gemm2_kernel(const u16* __restrict__ Hb,
                                                       const u16* __restrict__ W2,
                                                       const u16* __restrict__ WE,
                                                       const float* __restrict__ b2,
                                                       const float* __restrict__ be,
                                                       const int* __restrict__ idx,
                                                       float* __restrict__ Out) {
  constexpr int K = HH;       // 3072
  constexpr int NOUT = DD;    // 768
  __shared__ u16 As[96 * 64];    // 12 KB
  __shared__ u16 Bs[128 * 64];   // 16 KB
  const int tid = threadIdx.x;
  const int lane = tid & 63;
  const int wave = tid >> 6;
  const int m0 = blockIdx.x * 96;
  const int n0 = blockIdx.y * 128;
  const int wm = (wave >> 1) * 48;
  const int wn = (wave & 1) * 64;
  const int q = lane >> 4;
  const int r = lane & 15;
  const int xr = r & 7;

  const u16* Bbase;
  const float* biasp;
  if (n0 < SHARED_N) {
    Bbase = W2 + (long)n0 * K;
    biasp = b2 + n0;
  } else {
    const int e = idx[blockIdx.x >> 1];
    Bbase = WE + ((long)e * PP + (n0 - SHARED_N)) * K;
    biasp = be + e * PP + (n0 - SHARED_N);
  }
  const u16* Abase = Hb + (long)m0 * K;

  floatx4 acc[3][4] = {};

  int a_row[3], a_kcg[3], b_row[4], b_kcg[4];
#pragma unroll
  for (int i = 0; i < 3; ++i) {
    int c = i * 256 + tid;
    a_row[i] = c >> 3;
    a_kcg[i] = (c & 7) ^ (a_row[i] & 7);
  }
#pragma unroll
  for (int i = 0; i < 4; ++i) {
    int c = i * 256 + tid;
    b_row[i] = c >> 3;
    b_kcg[i] = (c & 7) ^ (b_row[i] & 7);
  }

  for (int kt = 0; kt < K / 64; ++kt) {
    const int k0 = kt * 64;
#pragma unroll
    for (int i = 0; i < 3; ++i)
      GLD16(Abase + (long)a_row[i] * K + k0 + a_kcg[i] * 8, &As[(i * 256 + tid) * 8]);
#pragma unroll
    for (int i = 0; i < 4; ++i)
      GLD16(Bbase + (long)b_row[i] * K + k0 + b_kcg[i] * 8, &Bs[(i * 256 + tid) * 8]);
    __syncthreads();

    short8 a[2][3], b[2][4];
#pragma unroll
    for (int ks = 0; ks < 2; ++ks) {
      const int kc = ks * 4 + q;
#pragma unroll
      for (int i = 0; i < 3; ++i)
        a[ks][i] = *(const short8*)&As[(((wm + i * 16 + r) << 3) + (kc ^ xr)) << 3];
#pragma unroll
      for (int j = 0; j < 4; ++j)
        b[ks][j] = *(const short8*)&Bs[(((wn + j * 16 + r) << 3) + (kc ^ xr)) << 3];
    }
#pragma unroll
    for (int ks = 0; ks < 2; ++ks)
#pragma unroll
      for (int i = 0; i < 3; ++i)
#pragma unroll
        for (int j = 0; j < 4; ++j)
          acc[i][j] = __builtin_amdgcn_mfma_f32_16x16x32_bf16(a[ks][i], b[ks][j], acc[i][j], 0, 0, 0);
    __syncthreads();
  }

#pragma unroll
  for (int j = 0; j < 4; ++j) {
    const int cl = wn + j * 16 + r;
    const int col = n0 + cl;
    const float bn = biasp[cl];
#pragma unroll
    for (int i = 0; i < 3; ++i) {
#pragma unroll
      for (int e = 0; e < 4; ++e) {
        const int row = m0 + wm + i * 16 + q * 4 + e;
        Out[(long)row * NOUT + col] = acc[i][j][e] + bn;
      }
    }
  }
}

extern "C" void kernel_launch(void* const* d_in, const int* in_sizes, int n_in,
                              void* d_out, int out_size, void* d_ws, size_t ws_size,
                              hipStream_t stream) {
  const float* x  = (const float*)d_in[0];   // [B,S,D]
  const int*  idx = (const int*)d_in[1];     // [B]
  const float* w1 = (const float*)d_in[2];   // [H,D]
  const float* b1 = (const float*)d_in[3];   // [H]
  const float* w2 = (const float*)d_in[4];   // [SHARED,H]
  const float* b2 = (const float*)d_in[5];   // [SHARED]
  const float* we = (const float*)d_in[6];   // [E,P,H]
  const float* be = (const float*)d_in[7];   // [E,P]
  float* out = (float*)d_out;

  u16* Xb  = (u16*)d_ws;                              // 12288*768
  u16* W1b = Xb  + N_X;                               // 3072*768
  u16* W2b = W1b + N_W1;                              // 512*3072
  u16* WEb = W2b + N_W2;                              // 6*256*3072
  u16* Hb  = WEb + N_WE;                              // 12288*3072

  cvt_all_kernel<<<(int)(N_ALL / 2048), 256, 0, stream>>>(x, w1, w2, we, Xb);
  gemm1_kernel<<<dim3(M_TOT / 128, HH / 128), 256, 0, stream>>>(Xb, W1b, b1, Hb);
  gemm2_kernel<<<dim3(M_TOT / 96, DD / 128), 256, 0, stream>>>(Hb, W2b, WEb, b2, be, idx, out);
}